// Round 6
// baseline (220.501 us; speedup 1.0000x reference)
//
#include <hip/hip_runtime.h>

namespace {
constexpr int B_ = 64, S_ = 200, DV_ = 128, NC2_ = 4096;
constexpr int FCH = 8, NFCH = 25;    // fill: 25 chunks x 8 rows
constexpr int ACH = 50, NACH = 4;    // alpha: 4 chunks x 50 rows
}

typedef float f4v __attribute__((ext_vector_type(4)));
typedef _Float16 h2v __attribute__((ext_vector_type(2)));

#if defined(__has_builtin)
#if __has_builtin(__builtin_amdgcn_fdot2)
#define HAVE_FDOT2 1
#endif
#endif

__device__ __forceinline__ float dot2acc(h2v a, h2v b, float c) {
#ifdef HAVE_FDOT2
  return __builtin_amdgcn_fdot2(a, b, c, false);
#else
  return c + (float)a.x * (float)b.x + (float)a.y * (float)b.y;
#endif
}

// LDS-only barrier: no vmcnt drain (no vmem ordering needed in the GRU loop).
__device__ __forceinline__ void lds_sync() {
  asm volatile("s_waitcnt lgkmcnt(0)\n\ts_barrier" ::: "memory");
}

// ---------------------------------------------------------------------------
// K1: blocks [0,64):  GRU per batch. 128 threads; thread d owns gate rows
//                     {d, d+128, d+256}; h history kept in LDS (f16);
//                     4 independent accumulator chains per gate (dep-chain
//                     depth 16 instead of 64). No vmem in step loop.
//     blocks [64,128): C2 value scan per batch, single wave, barrier-free.
// ---------------------------------------------------------------------------
__global__ __launch_bounds__(128, 1) void k1_gru_scan(
    const int* __restrict__ c2_seq, const int* __restrict__ d_seq,
    const int* __restrict__ r_seq, const float* __restrict__ D_emb,
    const float* __restrict__ v_d, const float* __restrict__ v_c2,
    const float* __restrict__ R_emb,
    const float* __restrict__ W_ih, const float* __restrict__ W_hh,
    const float* __restrict__ b_ih, const float* __restrict__ b_hh,
    const float* __restrict__ W3, const float* __restrict__ b3,
    const float* __restrict__ W4, const float* __restrict__ b4,
    float* __restrict__ out_h, float* __restrict__ vals_ws)
{
  __shared__ __align__(16) char smem[(S_ + 1) * DV_ * 2 + 2 * S_ * 4];
  const int tid = threadIdx.x;

  if (blockIdx.x < B_) {
    // ------------------ GRU for batch b ------------------
    const int b = blockIdx.x;
    _Float16* hist = reinterpret_cast<_Float16*>(smem);          // (S_+1)*DV_
    float* gl = reinterpret_cast<float*>(smem + (S_ + 1) * DV_ * 2);
    int* rl = reinterpret_cast<int*>(gl + S_);

    for (int i = tid; i < S_; i += 128) {
      gl[i] = D_emb[d_seq[b * S_ + i]];
      rl[i] = r_seq[b * S_ + i];
    }
    const int d = tid;  // 0..127
    // W_hh rows {d, d+128, d+256} as packed f16 pairs: 3 x 64 dwords
    h2v w[3][64];
#pragma unroll
    for (int g = 0; g < 3; ++g) {
      const float4* wr =
          reinterpret_cast<const float4*>(W_hh + (size_t)(d + g * DV_) * DV_);
#pragma unroll
      for (int k = 0; k < 32; ++k) {
        float4 t4 = wr[k];
        h2v lo, hi;
        lo.x = (_Float16)t4.x; lo.y = (_Float16)t4.y;
        hi.x = (_Float16)t4.z; hi.y = (_Float16)t4.w;
        w[g][2 * k] = lo; w[g][2 * k + 1] = hi;
      }
    }
    // collapsed input projections per gate row: xw = gamma*u + p_{r} (incl b_ih)
    float u[3], p0[3], p1[3], bh[3];
#pragma unroll
    for (int g = 0; g < 3; ++g) {
      const int row = d + g * DV_;
      const float4* wi =
          reinterpret_cast<const float4*>(W_ih + (size_t)row * 2 * DV_);
      const float4* vd4 = reinterpret_cast<const float4*>(v_d);
      const float4* re4 = reinterpret_cast<const float4*>(R_emb);
      float uu = 0.f, pp0 = 0.f, pp1 = 0.f;
#pragma unroll 8
      for (int k = 0; k < DV_ / 4; ++k) {
        float4 a = wi[k], vv = vd4[k];
        uu += a.x * vv.x + a.y * vv.y + a.z * vv.z + a.w * vv.w;
        float4 c = wi[DV_ / 4 + k];
        float4 r0 = re4[k], r1 = re4[DV_ / 4 + k];
        pp0 += c.x * r0.x + c.y * r0.y + c.z * r0.z + c.w * r0.w;
        pp1 += c.x * r1.x + c.y * r1.y + c.z * r1.z + c.w * r1.w;
      }
      const float bi = b_ih[row];
      u[g] = uu; p0[g] = pp0 + bi; p1[g] = pp1 + bi;
      bh[g] = b_hh[row];
    }
    float hreg = 0.f;
    hist[tid] = (_Float16)0.f;
    lds_sync();

    for (int t = 0; t < S_; ++t) {
      const float gv = gl[t];
      const int rv = rl[t];
      const float xr = gv * u[0] + (rv ? p1[0] : p0[0]);
      const float xz = gv * u[1] + (rv ? p1[1] : p0[1]);
      const float xn = gv * u[2] + (rv ? p1[2] : p0[2]);
      const float4* hb = reinterpret_cast<const float4*>(hist + t * DV_);
      // 4 independent accumulator chains per gate: dep depth 16, not 64.
      float a0[4] = {0.f, 0.f, 0.f, 0.f};
      float a1[4] = {0.f, 0.f, 0.f, 0.f};
      float a2[4] = {0.f, 0.f, 0.f, 0.f};
#pragma unroll
      for (int k = 0; k < 16; ++k) {
        float4 hv = hb[k];  // uniform address -> LDS broadcast
        h2v h0 = __builtin_bit_cast(h2v, hv.x);
        h2v h1 = __builtin_bit_cast(h2v, hv.y);
        h2v h2 = __builtin_bit_cast(h2v, hv.z);
        h2v h3 = __builtin_bit_cast(h2v, hv.w);
        a0[0] = dot2acc(w[0][4 * k + 0], h0, a0[0]);
        a1[0] = dot2acc(w[1][4 * k + 0], h0, a1[0]);
        a2[0] = dot2acc(w[2][4 * k + 0], h0, a2[0]);
        a0[1] = dot2acc(w[0][4 * k + 1], h1, a0[1]);
        a1[1] = dot2acc(w[1][4 * k + 1], h1, a1[1]);
        a2[1] = dot2acc(w[2][4 * k + 1], h1, a2[1]);
        a0[2] = dot2acc(w[0][4 * k + 2], h2, a0[2]);
        a1[2] = dot2acc(w[1][4 * k + 2], h2, a1[2]);
        a2[2] = dot2acc(w[2][4 * k + 2], h2, a2[2]);
        a0[3] = dot2acc(w[0][4 * k + 3], h3, a0[3]);
        a1[3] = dot2acc(w[1][4 * k + 3], h3, a1[3]);
        a2[3] = dot2acc(w[2][4 * k + 3], h3, a2[3]);
      }
      const float s0 = (a0[0] + a0[1]) + (a0[2] + a0[3]);
      const float s1 = (a1[0] + a1[1]) + (a1[2] + a1[3]);
      const float s2 = (a2[0] + a2[1]) + (a2[2] + a2[3]);
      const float r = 1.f / (1.f + __expf(-(xr + s0 + bh[0])));
      const float z = 1.f / (1.f + __expf(-(xz + s1 + bh[1])));
      const float nx = xn + r * (s2 + bh[2]);
      const float e2 = __expf(2.f * nx);
      const float n = (e2 - 1.f) / (e2 + 1.f);
      const float hnew = (1.f - z) * n + z * hreg;
      hreg = hnew;
      hist[(t + 1) * DV_ + d] = (_Float16)hnew;
      lds_sync();
    }

    // ---------- bulk dump h history (f16 -> f32) ----------
    const uint2* hu2 = reinterpret_cast<const uint2*>(hist + DV_);  // skip row0
    float4* op4 = reinterpret_cast<float4*>(out_h + (size_t)b * S_ * DV_);
    for (int i = tid; i < S_ * DV_ / 4; i += 128) {
      uint2 uu = hu2[i];
      h2v lo = __builtin_bit_cast(h2v, uu.x);
      h2v hi = __builtin_bit_cast(h2v, uu.y);
      float4 f;
      f.x = (float)lo.x; f.y = (float)lo.y;
      f.z = (float)hi.x; f.w = (float)hi.y;
      op4[i] = f;
    }
  } else {
    // ------------------ C2 value scan, single wave ------------------
    const int b = blockIdx.x - B_;
    float* C2s = reinterpret_cast<float*>(smem);                 // NC2_
    float* gl = C2s + NC2_;
    int* rl = reinterpret_cast<int*>(gl + S_);
    int* jl = rl + S_;   // fits: 16384+800+800+800 < 53856
    for (int i = tid; i < NC2_; i += 128) C2s[i] = 0.f;
    for (int i = tid; i < S_; i += 128) {
      gl[i] = D_emb[d_seq[b * S_ + i]];
      rl[i] = r_seq[b * S_ + i];
      jl[i] = c2_seq[b * S_ + i];
    }
    __syncthreads();
    if (tid >= 64) return;
    const int lane = tid;
    float a3L = 0, u3L = 0, q0L = 0, q1L = 0;
    float a3H = 0, u3H = 0, q0H = 0, q1H = 0;
    {
      const float4* vc4 = reinterpret_cast<const float4*>(v_c2);
      const float4* vd4 = reinterpret_cast<const float4*>(v_d);
      const float4* re4 = reinterpret_cast<const float4*>(R_emb);
      const float4* wL = reinterpret_cast<const float4*>(W3 + (size_t)lane * 3 * DV_);
      const float4* wH = reinterpret_cast<const float4*>(W3 + (size_t)(lane + 64) * 3 * DV_);
#pragma unroll 8
      for (int k = 0; k < DV_ / 4; ++k) {
        float4 cc = vc4[k], dd = vd4[k];
        float4 r0 = re4[k], r1 = re4[DV_ / 4 + k];
        float4 aL = wL[k], aH = wH[k];
        a3L += aL.x * cc.x + aL.y * cc.y + aL.z * cc.z + aL.w * cc.w;
        a3H += aH.x * cc.x + aH.y * cc.y + aH.z * cc.z + aH.w * cc.w;
        float4 bL = wL[DV_ / 4 + k], bH = wH[DV_ / 4 + k];
        u3L += bL.x * dd.x + bL.y * dd.y + bL.z * dd.z + bL.w * dd.w;
        u3H += bH.x * dd.x + bH.y * dd.y + bH.z * dd.z + bH.w * dd.w;
        float4 cL = wL[2 * (DV_ / 4) + k], cH = wH[2 * (DV_ / 4) + k];
        q0L += cL.x * r0.x + cL.y * r0.y + cL.z * r0.z + cL.w * r0.w;
        q1L += cL.x * r1.x + cL.y * r1.y + cL.z * r1.z + cL.w * r1.w;
        q0H += cH.x * r0.x + cH.y * r0.y + cH.z * r0.z + cH.w * r0.w;
        q1H += cH.x * r1.x + cH.y * r1.y + cH.z * r1.z + cH.w * r1.w;
      }
      float bbL = b3[lane], bbH = b3[lane + 64];
      q0L += bbL; q1L += bbL; q0H += bbH; q1H += bbH;
    }
    const float w4L = W4[lane], w4H = W4[lane + 64];
    const float b4v = b4[0];

    int jc = jl[0];
    float gv = gl[0];
    int rv = rl[0];
    float pf = 0.f;
    float lastv = 0.f;
    int lastj = -1;
    for (int t = 0; t < S_; ++t) {
      const int tn = (t + 1 < S_) ? t + 1 : 0;
      const int jn = jl[tn];
      const float gvn = gl[tn];
      const int rvn = rl[tn];
      const float pfn = C2s[jn];   // prefetch; patched via lastj/lastv
      const float beta = (jc == lastj) ? lastv : pf;
      float hL = beta * a3L + gv * u3L + (rv ? q1L : q0L);
      float hH = beta * a3H + gv * u3H + (rv ? q1H : q0H);
      float part = fmaxf(hL, 0.f) * w4L + fmaxf(hH, 0.f) * w4H;
#pragma unroll
      for (int off = 1; off < 64; off <<= 1) part += __shfl_xor(part, off);
      const float val = part + b4v;
      if (lane == 0) {
        C2s[jc] = val;
        vals_ws[b * S_ + t] = val;
      }
      lastj = jc; lastv = val;
      jc = jn; gv = gvn; rv = rvn; pf = pfn;
    }
  }
}

// ---------------------------------------------------------------------------
// K2: blocks [0,256):    alpha MLP, (b, 50-row chunk)
//     blocks [256,1856): C2_seq fill, (b, 8-row chunk), barrier-free rows
// ---------------------------------------------------------------------------
__global__ __launch_bounds__(256) void k2_alpha_fill(
    const int* __restrict__ c2_seq,
    const float* __restrict__ W1, const float* __restrict__ b1,
    const float* __restrict__ W2, const float* __restrict__ b2,
    const float* __restrict__ vals_ws, const float* __restrict__ h_seq,
    float* __restrict__ out_alpha, float* __restrict__ out_c2)
{
  const int tid = threadIdx.x;
  if (blockIdx.x < NACH * B_) {
    // ------------------ alpha ------------------
    const int b = blockIdx.x >> 2, c = blockIdx.x & 3;
    const int sbeg = c * ACH, send = sbeg + ACH;
    __shared__ float4 hb4[2][DV_ / 4];
    __shared__ float red[4];
    const int grp = tid >> 7, d = tid & 127;
    float w1r[DV_];
    {
      const float4* wr = reinterpret_cast<const float4*>(W1 + (size_t)d * DV_);
#pragma unroll
      for (int k = 0; k < DV_ / 4; ++k) {
        float4 t4 = wr[k];
        w1r[4 * k] = t4.x; w1r[4 * k + 1] = t4.y;
        w1r[4 * k + 2] = t4.z; w1r[4 * k + 3] = t4.w;
      }
    }
    const float b1v = b1[d], w2v = W2[d], b2v = b2[0];
    float* hb = reinterpret_cast<float*>(hb4[grp]);
    for (int s = sbeg; s < send; s += 2) {
      const int ss = s + grp;
      hb[d] = h_seq[((size_t)(b * S_ + ss)) * DV_ + d];
      __syncthreads();
      float y0 = b1v, y1 = 0, y2 = 0, y3 = 0;
#pragma unroll
      for (int k = 0; k < DV_ / 4; ++k) {
        float4 hv = hb4[grp][k];
        y0 += w1r[4 * k + 0] * hv.x; y1 += w1r[4 * k + 1] * hv.y;
        y2 += w1r[4 * k + 2] * hv.z; y3 += w1r[4 * k + 3] * hv.w;
      }
      float part = w2v * fmaxf((y0 + y1) + (y2 + y3), 0.f);
#pragma unroll
      for (int off = 1; off < 64; off <<= 1) part += __shfl_xor(part, off);
      if ((tid & 63) == 0) red[tid >> 6] = part;
      __syncthreads();
      if (d == 0) out_alpha[b * S_ + ss] = red[2 * grp] + red[2 * grp + 1] + b2v;
      __syncthreads();
    }
  } else {
    // ------------------ C2_seq fill ------------------
    const int blk = blockIdx.x - NACH * B_;
    const int b = blk / NFCH, c = blk % NFCH;
    const int s0 = c * FCH;
    __shared__ float vls[S_];
    __shared__ int jl[S_];
    for (int i = tid; i < S_; i += 256) {
      vls[i] = vals_ws[b * S_ + i];
      jl[i] = c2_seq[b * S_ + i];
    }
    __syncthreads();
    // thread owns 16 columns: float4 indices f = tid + jj*256
    f4v v0 = {0.f, 0.f, 0.f, 0.f}, v1 = v0, v2 = v0, v3 = v0;

#define APPLY_EVT(T)                                                          \
    {                                                                         \
      const int j_ = jl[(T)];                                                 \
      const int f_ = j_ >> 2;                                                 \
      if ((f_ & 255) == tid) {                                                \
        const float vv_ = vls[(T)];                                           \
        const int rr_ = f_ >> 8, q_ = j_ & 3;                                 \
        if (rr_ == 0) {                                                       \
          if (q_ == 0) v0.x = vv_; else if (q_ == 1) v0.y = vv_;              \
          else if (q_ == 2) v0.z = vv_; else v0.w = vv_;                      \
        } else if (rr_ == 1) {                                                \
          if (q_ == 0) v1.x = vv_; else if (q_ == 1) v1.y = vv_;              \
          else if (q_ == 2) v1.z = vv_; else v1.w = vv_;                      \
        } else if (rr_ == 2) {                                                \
          if (q_ == 0) v2.x = vv_; else if (q_ == 1) v2.y = vv_;              \
          else if (q_ == 2) v2.z = vv_; else v2.w = vv_;                      \
        } else {                                                              \
          if (q_ == 0) v3.x = vv_; else if (q_ == 1) v3.y = vv_;              \
          else if (q_ == 2) v3.z = vv_; else v3.w = vv_;                      \
        }                                                                     \
      }                                                                       \
    }

    for (int t = 0; t < s0; ++t) APPLY_EVT(t);

    f4v* dst4 = reinterpret_cast<f4v*>(out_c2 + (size_t)b * S_ * NC2_);
    for (int s = s0; s < s0 + FCH; ++s) {
      APPLY_EVT(s);
      f4v* drow = dst4 + (size_t)s * (NC2_ / 4);
      __builtin_nontemporal_store(v0, drow + tid);
      __builtin_nontemporal_store(v1, drow + tid + 256);
      __builtin_nontemporal_store(v2, drow + tid + 512);
      __builtin_nontemporal_store(v3, drow + tid + 768);
    }
#undef APPLY_EVT
  }
}

extern "C" void kernel_launch(void* const* d_in, const int* in_sizes, int n_in,
                              void* d_out, int out_size, void* d_ws, size_t ws_size,
                              hipStream_t stream) {
  const int* c2_seq = (const int*)d_in[1];
  const int* d_seq = (const int*)d_in[3];
  const int* r_seq = (const int*)d_in[4];
  const float* D_emb = (const float*)d_in[5];
  const float* v_d = (const float*)d_in[6];
  const float* v_c2 = (const float*)d_in[7];
  const float* R_emb = (const float*)d_in[8];
  const float* W_ih = (const float*)d_in[9];
  const float* W_hh = (const float*)d_in[10];
  const float* b_ih = (const float*)d_in[11];
  const float* b_hh = (const float*)d_in[12];
  const float* W1 = (const float*)d_in[13];
  const float* b1 = (const float*)d_in[14];
  const float* W2 = (const float*)d_in[15];
  const float* b2 = (const float*)d_in[16];
  const float* W3 = (const float*)d_in[17];
  const float* b3 = (const float*)d_in[18];
  const float* W4 = (const float*)d_in[19];
  const float* b4 = (const float*)d_in[20];

  float* out = (float*)d_out;
  float* out_alpha = out;                                  // [B,S]
  float* out_h = out + B_ * S_;                            // [B,S,DV]
  float* out_c2 = out + B_ * S_ + (size_t)B_ * S_ * DV_;   // [B,S,NC2]
  float* vals_ws = (float*)d_ws;                           // [B*S] floats

  k1_gru_scan<<<dim3(2 * B_), dim3(128), 0, stream>>>(
      c2_seq, d_seq, r_seq, D_emb, v_d, v_c2, R_emb, W_ih, W_hh, b_ih, b_hh,
      W3, b3, W4, b4, out_h, vals_ws);
  k2_alpha_fill<<<dim3(NACH * B_ + B_ * NFCH), dim3(256), 0, stream>>>(
      c2_seq, W1, b1, W2, b2, vals_ws, out_h, out_alpha, out_c2);
}

// Round 8
// 194.762 us; speedup vs baseline: 1.1322x; 1.1322x over previous
//
#include <hip/hip_runtime.h>

namespace {
constexpr int B_ = 64, S_ = 200, DV_ = 128, NC2_ = 4096;
constexpr int FCH = 8, NFCH = 25;    // fill: 25 chunks x 8 rows
constexpr int ACH = 50, NACH = 4;    // alpha: 4 chunks x 50 rows
}

typedef float f4v __attribute__((ext_vector_type(4)));
typedef _Float16 h2v __attribute__((ext_vector_type(2)));

#if defined(__has_builtin)
#if __has_builtin(__builtin_amdgcn_fdot2)
#define HAVE_FDOT2 1
#endif
#endif

__device__ __forceinline__ float dot2acc(h2v a, h2v b, float c) {
#ifdef HAVE_FDOT2
  return __builtin_amdgcn_fdot2(a, b, c, false);
#else
  return c + (float)a.x * (float)b.x + (float)a.y * (float)b.y;
#endif
}

// LDS-only barrier: no vmcnt drain (no vmem ordering needed in the GRU loop).
__device__ __forceinline__ void lds_sync() {
  asm volatile("s_waitcnt lgkmcnt(0)\n\ts_barrier" ::: "memory");
}

// ---------------------------------------------------------------------------
// K1: blocks [0,64):  GRU per batch. 256 threads = (d, p) pairs: thread pair
//                     splits K; per-thread weights w[3][32] (96 VGPRs -> no
//                     spill). One shfl_xor(.,1) per gate; one barrier/step.
//                     h history in LDS (f16); bulk dump at end.
//     blocks [64,128): C2 value scan per batch, single wave, barrier-free.
// ---------------------------------------------------------------------------
__global__ __launch_bounds__(256, 1) void k1_gru_scan(
    const int* __restrict__ c2_seq, const int* __restrict__ d_seq,
    const int* __restrict__ r_seq, const float* __restrict__ D_emb,
    const float* __restrict__ v_d, const float* __restrict__ v_c2,
    const float* __restrict__ R_emb,
    const float* __restrict__ W_ih, const float* __restrict__ W_hh,
    const float* __restrict__ b_ih, const float* __restrict__ b_hh,
    const float* __restrict__ W3, const float* __restrict__ b3,
    const float* __restrict__ W4, const float* __restrict__ b4,
    float* __restrict__ out_h, float* __restrict__ vals_ws)
{
  __shared__ __align__(16) char smem[(S_ + 1) * DV_ * 2 + 2 * S_ * 4];
  const int tid = threadIdx.x;

  if (blockIdx.x < B_) {
    // ------------------ GRU for batch b ------------------
    const int b = blockIdx.x;
    _Float16* hist = reinterpret_cast<_Float16*>(smem);          // (S_+1)*DV_
    float* gl = reinterpret_cast<float*>(smem + (S_ + 1) * DV_ * 2);
    int* rl = reinterpret_cast<int*>(gl + S_);

    for (int i = tid; i < S_; i += 256) {
      gl[i] = D_emb[d_seq[b * S_ + i]];
      rl[i] = r_seq[b * S_ + i];
    }
    const int d = tid >> 1;   // output dim 0..127
    const int p = tid & 1;    // K-half (adjacent lanes -> shfl_xor(.,1))
    // W_hh rows {d, d+128, d+256}, K-half p, packed f16 pairs: 3 x 32 dwords
    h2v w[3][32];
#pragma unroll
    for (int g = 0; g < 3; ++g) {
      const float4* wr = reinterpret_cast<const float4*>(
          W_hh + (size_t)(d + g * DV_) * DV_ + p * 64);
#pragma unroll
      for (int k = 0; k < 16; ++k) {
        float4 t4 = wr[k];
        h2v lo, hi;
        lo.x = (_Float16)t4.x; lo.y = (_Float16)t4.y;
        hi.x = (_Float16)t4.z; hi.y = (_Float16)t4.w;
        w[g][2 * k] = lo; w[g][2 * k + 1] = hi;
      }
    }
    // collapsed input projections per gate row (redundant across the pair)
    float u[3], p0[3], p1[3], bh[3];
#pragma unroll
    for (int g = 0; g < 3; ++g) {
      const int row = d + g * DV_;
      const float4* wi =
          reinterpret_cast<const float4*>(W_ih + (size_t)row * 2 * DV_);
      const float4* vd4 = reinterpret_cast<const float4*>(v_d);
      const float4* re4 = reinterpret_cast<const float4*>(R_emb);
      float uu = 0.f, pp0 = 0.f, pp1 = 0.f;
#pragma unroll 8
      for (int k = 0; k < DV_ / 4; ++k) {
        float4 a = wi[k], vv = vd4[k];
        uu += a.x * vv.x + a.y * vv.y + a.z * vv.z + a.w * vv.w;
        float4 c = wi[DV_ / 4 + k];
        float4 r0 = re4[k], r1 = re4[DV_ / 4 + k];
        pp0 += c.x * r0.x + c.y * r0.y + c.z * r0.z + c.w * r0.w;
        pp1 += c.x * r1.x + c.y * r1.y + c.z * r1.z + c.w * r1.w;
      }
      const float bi = b_ih[row];
      u[g] = uu; p0[g] = pp0 + bi; p1[g] = pp1 + bi;
      bh[g] = b_hh[row];
    }
    float hreg = 0.f;
    if (tid < DV_) hist[tid] = (_Float16)0.f;
    lds_sync();

    float gv = gl[0];
    int rv = rl[0];
    for (int t = 0; t < S_; ++t) {
      const float xr = gv * u[0] + (rv ? p1[0] : p0[0]);
      const float xz = gv * u[1] + (rv ? p1[1] : p0[1]);
      const float xn = gv * u[2] + (rv ? p1[2] : p0[2]);
      const float4* hb = reinterpret_cast<const float4*>(hist + t * DV_);
      // 4 independent chains per gate, depth 8. Half-row = 64 f16 = 8 float4.
      float a0[4] = {0.f, 0.f, 0.f, 0.f};
      float a1[4] = {0.f, 0.f, 0.f, 0.f};
      float a2[4] = {0.f, 0.f, 0.f, 0.f};
#pragma unroll
      for (int k = 0; k < 8; ++k) {
        float4 hv = hb[p * 8 + k];  // 2 addrs/wave -> 2-way, free
        h2v h0 = __builtin_bit_cast(h2v, hv.x);
        h2v h1 = __builtin_bit_cast(h2v, hv.y);
        h2v h2 = __builtin_bit_cast(h2v, hv.z);
        h2v h3 = __builtin_bit_cast(h2v, hv.w);
        a0[0] = dot2acc(w[0][4 * k + 0], h0, a0[0]);
        a1[0] = dot2acc(w[1][4 * k + 0], h0, a1[0]);
        a2[0] = dot2acc(w[2][4 * k + 0], h0, a2[0]);
        a0[1] = dot2acc(w[0][4 * k + 1], h1, a0[1]);
        a1[1] = dot2acc(w[1][4 * k + 1], h1, a1[1]);
        a2[1] = dot2acc(w[2][4 * k + 1], h1, a2[1]);
        a0[2] = dot2acc(w[0][4 * k + 2], h2, a0[2]);
        a1[2] = dot2acc(w[1][4 * k + 2], h2, a1[2]);
        a2[2] = dot2acc(w[2][4 * k + 2], h2, a2[2]);
        a0[3] = dot2acc(w[0][4 * k + 3], h3, a0[3]);
        a1[3] = dot2acc(w[1][4 * k + 3], h3, a1[3]);
        a2[3] = dot2acc(w[2][4 * k + 3], h3, a2[3]);
      }
      float s0 = (a0[0] + a0[1]) + (a0[2] + a0[3]);
      float s1 = (a1[0] + a1[1]) + (a1[2] + a1[3]);
      float s2 = (a2[0] + a2[1]) + (a2[2] + a2[3]);
      s0 += __shfl_xor(s0, 1);
      s1 += __shfl_xor(s1, 1);
      s2 += __shfl_xor(s2, 1);
      const float r = 1.f / (1.f + __expf(-(xr + s0 + bh[0])));
      const float z = 1.f / (1.f + __expf(-(xz + s1 + bh[1])));
      const float nx = xn + r * (s2 + bh[2]);
      const float e2 = __expf(2.f * nx);
      const float n = (e2 - 1.f) / (e2 + 1.f);
      const float hnew = (1.f - z) * n + z * hreg;
      hreg = hnew;
      if (p == 0) hist[(t + 1) * DV_ + d] = (_Float16)hnew;
      if (t + 1 < S_) {            // prefetch next scalars before barrier
        gv = gl[t + 1];
        rv = rl[t + 1];
      }
      lds_sync();
    }

    // ---------- bulk dump h history (f16 -> f32) ----------
    const uint2* hu2 = reinterpret_cast<const uint2*>(hist + DV_);  // skip row0
    float4* op4 = reinterpret_cast<float4*>(out_h + (size_t)b * S_ * DV_);
    for (int i = tid; i < S_ * DV_ / 4; i += 256) {
      uint2 uu = hu2[i];
      h2v lo = __builtin_bit_cast(h2v, uu.x);
      h2v hi = __builtin_bit_cast(h2v, uu.y);
      float4 f;
      f.x = (float)lo.x; f.y = (float)lo.y;
      f.z = (float)hi.x; f.w = (float)hi.y;
      op4[i] = f;
    }
  } else {
    // ------------------ C2 value scan, single wave ------------------
    const int b = blockIdx.x - B_;
    float* C2s = reinterpret_cast<float*>(smem);                 // NC2_
    float* gl = C2s + NC2_;
    int* rl = reinterpret_cast<int*>(gl + S_);
    int* jl = rl + S_;
    for (int i = tid; i < NC2_; i += 256) C2s[i] = 0.f;
    for (int i = tid; i < S_; i += 256) {
      gl[i] = D_emb[d_seq[b * S_ + i]];
      rl[i] = r_seq[b * S_ + i];
      jl[i] = c2_seq[b * S_ + i];
    }
    __syncthreads();
    if (tid >= 64) return;
    const int lane = tid;
    float a3L = 0, u3L = 0, q0L = 0, q1L = 0;
    float a3H = 0, u3H = 0, q0H = 0, q1H = 0;
    {
      const float4* vc4 = reinterpret_cast<const float4*>(v_c2);
      const float4* vd4 = reinterpret_cast<const float4*>(v_d);
      const float4* re4 = reinterpret_cast<const float4*>(R_emb);
      const float4* wL = reinterpret_cast<const float4*>(W3 + (size_t)lane * 3 * DV_);
      const float4* wH = reinterpret_cast<const float4*>(W3 + (size_t)(lane + 64) * 3 * DV_);
#pragma unroll 8
      for (int k = 0; k < DV_ / 4; ++k) {
        float4 cc = vc4[k], dd = vd4[k];
        float4 r0 = re4[k], r1 = re4[DV_ / 4 + k];
        float4 aL = wL[k], aH = wH[k];
        a3L += aL.x * cc.x + aL.y * cc.y + aL.z * cc.z + aL.w * cc.w;
        a3H += aH.x * cc.x + aH.y * cc.y + aH.z * cc.z + aH.w * cc.w;
        float4 bL = wL[DV_ / 4 + k], bH = wH[DV_ / 4 + k];
        u3L += bL.x * dd.x + bL.y * dd.y + bL.z * dd.z + bL.w * dd.w;
        u3H += bH.x * dd.x + bH.y * dd.y + bH.z * dd.z + bH.w * dd.w;
        float4 cL = wL[2 * (DV_ / 4) + k], cH = wH[2 * (DV_ / 4) + k];
        q0L += cL.x * r0.x + cL.y * r0.y + cL.z * r0.z + cL.w * r0.w;
        q1L += cL.x * r1.x + cL.y * r1.y + cL.z * r1.z + cL.w * r1.w;
        q0H += cH.x * r0.x + cH.y * r0.y + cH.z * r0.z + cH.w * r0.w;
        q1H += cH.x * r1.x + cH.y * r1.y + cH.z * r1.z + cH.w * r1.w;
      }
      float bbL = b3[lane], bbH = b3[lane + 64];
      q0L += bbL; q1L += bbL; q0H += bbH; q1H += bbH;
    }
    const float w4L = W4[lane], w4H = W4[lane + 64];
    const float b4v = b4[0];

    int jc = jl[0];
    float gv = gl[0];
    int rv = rl[0];
    float pf = 0.f;
    float lastv = 0.f;
    int lastj = -1;
    for (int t = 0; t < S_; ++t) {
      const int tn = (t + 1 < S_) ? t + 1 : 0;
      const int jn = jl[tn];
      const float gvn = gl[tn];
      const int rvn = rl[tn];
      const float pfn = C2s[jn];   // prefetch; patched via lastj/lastv
      const float beta = (jc == lastj) ? lastv : pf;
      float hL = beta * a3L + gv * u3L + (rv ? q1L : q0L);
      float hH = beta * a3H + gv * u3H + (rv ? q1H : q0H);
      float part = fmaxf(hL, 0.f) * w4L + fmaxf(hH, 0.f) * w4H;
#pragma unroll
      for (int off = 1; off < 64; off <<= 1) part += __shfl_xor(part, off);
      const float val = part + b4v;
      if (lane == 0) {
        C2s[jc] = val;
        vals_ws[b * S_ + t] = val;
      }
      lastj = jc; lastv = val;
      jc = jn; gv = gvn; rv = rvn; pf = pfn;
    }
  }
}

// ---------------------------------------------------------------------------
// K2: blocks [0,256):    alpha MLP, (b, 50-row chunk)
//     blocks [256,1856): C2_seq fill, (b, 8-row chunk), barrier-free rows
// ---------------------------------------------------------------------------
__global__ __launch_bounds__(256) void k2_alpha_fill(
    const int* __restrict__ c2_seq,
    const float* __restrict__ W1, const float* __restrict__ b1,
    const float* __restrict__ W2, const float* __restrict__ b2,
    const float* __restrict__ vals_ws, const float* __restrict__ h_seq,
    float* __restrict__ out_alpha, float* __restrict__ out_c2)
{
  const int tid = threadIdx.x;
  if (blockIdx.x < NACH * B_) {
    // ------------------ alpha ------------------
    const int b = blockIdx.x >> 2, c = blockIdx.x & 3;
    const int sbeg = c * ACH, send = sbeg + ACH;
    __shared__ float4 hb4[2][DV_ / 4];
    __shared__ float red[4];
    const int grp = tid >> 7, d = tid & 127;
    float w1r[DV_];
    {
      const float4* wr = reinterpret_cast<const float4*>(W1 + (size_t)d * DV_);
#pragma unroll
      for (int k = 0; k < DV_ / 4; ++k) {
        float4 t4 = wr[k];
        w1r[4 * k] = t4.x; w1r[4 * k + 1] = t4.y;
        w1r[4 * k + 2] = t4.z; w1r[4 * k + 3] = t4.w;
      }
    }
    const float b1v = b1[d], w2v = W2[d], b2v = b2[0];
    float* hb = reinterpret_cast<float*>(hb4[grp]);
    for (int s = sbeg; s < send; s += 2) {
      const int ss = s + grp;
      hb[d] = h_seq[((size_t)(b * S_ + ss)) * DV_ + d];
      __syncthreads();
      float y0 = b1v, y1 = 0, y2 = 0, y3 = 0;
#pragma unroll
      for (int k = 0; k < DV_ / 4; ++k) {
        float4 hv = hb4[grp][k];
        y0 += w1r[4 * k + 0] * hv.x; y1 += w1r[4 * k + 1] * hv.y;
        y2 += w1r[4 * k + 2] * hv.z; y3 += w1r[4 * k + 3] * hv.w;
      }
      float part = w2v * fmaxf((y0 + y1) + (y2 + y3), 0.f);
#pragma unroll
      for (int off = 1; off < 64; off <<= 1) part += __shfl_xor(part, off);
      if ((tid & 63) == 0) red[tid >> 6] = part;
      __syncthreads();
      if (d == 0) out_alpha[b * S_ + ss] = red[2 * grp] + red[2 * grp + 1] + b2v;
      __syncthreads();
    }
  } else {
    // ------------------ C2_seq fill ------------------
    const int blk = blockIdx.x - NACH * B_;
    const int b = blk / NFCH, c = blk % NFCH;
    const int s0 = c * FCH;
    __shared__ float vls[S_];
    __shared__ int jl[S_];
    for (int i = tid; i < S_; i += 256) {
      vls[i] = vals_ws[b * S_ + i];
      jl[i] = c2_seq[b * S_ + i];
    }
    __syncthreads();
    // thread owns 16 columns: float4 indices f = tid + jj*256
    f4v v0 = {0.f, 0.f, 0.f, 0.f}, v1 = v0, v2 = v0, v3 = v0;

#define APPLY_EVT(T)                                                          \
    {                                                                         \
      const int j_ = jl[(T)];                                                 \
      const int f_ = j_ >> 2;                                                 \
      if ((f_ & 255) == tid) {                                                \
        const float vv_ = vls[(T)];                                           \
        const int rr_ = f_ >> 8, q_ = j_ & 3;                                 \
        if (rr_ == 0) {                                                       \
          if (q_ == 0) v0.x = vv_; else if (q_ == 1) v0.y = vv_;              \
          else if (q_ == 2) v0.z = vv_; else v0.w = vv_;                      \
        } else if (rr_ == 1) {                                                \
          if (q_ == 0) v1.x = vv_; else if (q_ == 1) v1.y = vv_;              \
          else if (q_ == 2) v1.z = vv_; else v1.w = vv_;                      \
        } else if (rr_ == 2) {                                                \
          if (q_ == 0) v2.x = vv_; else if (q_ == 1) v2.y = vv_;              \
          else if (q_ == 2) v2.z = vv_; else v2.w = vv_;                      \
        } else {                                                              \
          if (q_ == 0) v3.x = vv_; else if (q_ == 1) v3.y = vv_;              \
          else if (q_ == 2) v3.z = vv_; else v3.w = vv_;                      \
        }                                                                     \
      }                                                                       \
    }

    for (int t = 0; t < s0; ++t) APPLY_EVT(t);

    f4v* dst4 = reinterpret_cast<f4v*>(out_c2 + (size_t)b * S_ * NC2_);
    for (int s = s0; s < s0 + FCH; ++s) {
      APPLY_EVT(s);
      f4v* drow = dst4 + (size_t)s * (NC2_ / 4);
      __builtin_nontemporal_store(v0, drow + tid);
      __builtin_nontemporal_store(v1, drow + tid + 256);
      __builtin_nontemporal_store(v2, drow + tid + 512);
      __builtin_nontemporal_store(v3, drow + tid + 768);
    }
#undef APPLY_EVT
  }
}

extern "C" void kernel_launch(void* const* d_in, const int* in_sizes, int n_in,
                              void* d_out, int out_size, void* d_ws, size_t ws_size,
                              hipStream_t stream) {
  const int* c2_seq = (const int*)d_in[1];
  const int* d_seq = (const int*)d_in[3];
  const int* r_seq = (const int*)d_in[4];
  const float* D_emb = (const float*)d_in[5];
  const float* v_d = (const float*)d_in[6];
  const float* v_c2 = (const float*)d_in[7];
  const float* R_emb = (const float*)d_in[8];
  const float* W_ih = (const float*)d_in[9];
  const float* W_hh = (const float*)d_in[10];
  const float* b_ih = (const float*)d_in[11];
  const float* b_hh = (const float*)d_in[12];
  const float* W1 = (const float*)d_in[13];
  const float* b1 = (const float*)d_in[14];
  const float* W2 = (const float*)d_in[15];
  const float* b2 = (const float*)d_in[16];
  const float* W3 = (const float*)d_in[17];
  const float* b3 = (const float*)d_in[18];
  const float* W4 = (const float*)d_in[19];
  const float* b4 = (const float*)d_in[20];

  float* out = (float*)d_out;
  float* out_alpha = out;                                  // [B,S]
  float* out_h = out + B_ * S_;                            // [B,S,DV]
  float* out_c2 = out + B_ * S_ + (size_t)B_ * S_ * DV_;   // [B,S,NC2]
  float* vals_ws = (float*)d_ws;                           // [B*S] floats

  k1_gru_scan<<<dim3(2 * B_), dim3(256), 0, stream>>>(
      c2_seq, d_seq, r_seq, D_emb, v_d, v_c2, R_emb, W_ih, W_hh, b_ih, b_hh,
      W3, b3, W4, b4, out_h, vals_ws);
  k2_alpha_fill<<<dim3(NACH * B_ + B_ * NFCH), dim3(256), 0, stream>>>(
      c2_seq, W1, b1, W2, b2, vals_ws, out_h, out_alpha, out_c2);
}